// Round 11
// baseline (1788.701 us; speedup 1.0000x reference)
//
#include <hip/hip_runtime.h>
#include <math.h>

#define NN 4096
#define TT 64
#define HH 128
#define NNP 4160            // hinT row stride (shorts): 8320B kills 8KB L2 set-aliasing
#define SLICE (128 * NNP)   // shorts per hinT time-slice
#define SPLITS 8
#define KPB (NN / SPLITS)   // 512 keys per phase-A block
#define KT 32
#define NTILES (KPB / KT)   // 16
#define QB 64               // q rows per attn block
#define SCALE 0.08838834764831845f   // 1/sqrt(128)
#define CSHIFT 16.0f

typedef __attribute__((ext_vector_type(8))) short short8;
typedef __attribute__((ext_vector_type(4))) float f32x4;
typedef unsigned long long u64;
#define MFMA(a, b, c)   __builtin_amdgcn_mfma_f32_16x16x32_bf16((a), (b), (c), 0, 0, 0)

// ---- bf16 helpers (RNE) ----
__device__ __forceinline__ short f2b(float f) {
    union { float f; unsigned u; } v; v.f = f;
    unsigned r = v.u + 0x7fffu + ((v.u >> 16) & 1u);
    return (short)(r >> 16);
}
__device__ __forceinline__ float b2f(short s) {
    union { unsigned u; float f; } v; v.u = ((unsigned)(unsigned short)s) << 16;
    return v.f;
}
// Wave-local LDS fence: completes ds ops + blocks compiler reordering of
// cross-lane LDS accesses without a block barrier.
__device__ __forceinline__ void lds_fence() {
    __asm__ __volatile__("s_waitcnt lgkmcnt(0)" ::: "memory");
}

// ===========================================================================
// hinT column permutation sigma (within each 32-column group):
//   column c holds node  sigma(c) = (c&4) ? 16 + 4*(c>>3) + (c&3)
//                                         :      4*(c>>3) + (c&3)
// Writers place node kk at column inv_sigma(kk) = ((kk>>2)&3)*8 +
// ((kk>>4)&1)*4 + (kk&3)  (maps aligned-4 node chunks -> aligned-4 columns).
// After swapped QK^T (st = MFMA(K,Q) -> D[key][q]), lane (ln,g) holds the 8
// P-values of its query for keys {4g..4g+3, 16+4g..16+4g+3} — exactly a
// 16x16x32 PV A-fragment under sigma on the key axis (dot-product axis:
// permuting BOTH operands is free).  R3-proven end to end.  l accumulates on
// the matrix pipe via a B=ones MFMA (R5-R8 proven).  cvt_pk inline asm
// BANNED (NaN R1/2/4).  Coop grid.sync BANNED (R6: L2 invalidation).
// R10 lesson (this round): attn was LDS-read-bound (~10.7 us/step of frag
// reads at 16 reads per 17 MFMAs).  Key-split waves — wave (qh,kh) computes
// 2 q-tiles on half the keys — halve frag reads at equal per-tile MFMA
// density; key-halves merge in fp32 via LDS post-loop.
// ===========================================================================

// ===========================================================================
// prep: once per launch. bf16 weight transposes; hp = b_proj (h0=0);
// hinT_all (64 slices, padded stride NNP, sigma-permuted columns) for ALL t.
// grid: 256 (hp) + 16 (weights) + 4096 (64 t x 64 n-groups, LDS-transposed).
// ===========================================================================
__global__ __launch_bounds__(256) void prep_kernel(
    const float* __restrict__ x_seq, const float* __restrict__ m_seq,
    const float* __restrict__ W_in,  const float* __restrict__ b_in,
    const float* __restrict__ W_proj,const float* __restrict__ b_proj,
    const float* __restrict__ W_gcn,
    short* __restrict__ hp, short* __restrict__ hinT_all,
    short* __restrict__ WgT, short* __restrict__ WpT)
{
    __shared__ __align__(16) short hb[128 * 66];   // [j][q], stride 66: bank-safe
    const int b = blockIdx.x, tid = threadIdx.x;
    if (b < 256) {
        const int n0 = b * 16;
        for (int i = tid; i < 16 * HH; i += 256) {
            const int q = i >> 7, j = i & 127, n = n0 + q;
            hp[n * HH + j] = f2b(b_proj[j]);
        }
    } else if (b < 272) {
        const int wb = b - 256;
        #pragma unroll
        for (int k = 0; k < 4; ++k) {
            const int idx = wb * 1024 + k * 256 + tid;   // = n*128 + kk
            const int n = idx >> 7, kk = idx & 127;
            WgT[idx] = f2b(W_gcn[kk * HH + n]);
            WpT[idx] = f2b(W_proj[kk * HH + n]);
        }
    } else {
        const int u = b - 272;
        const int t = u >> 6, n0 = (u & 63) * 64;
        // compute h_in for 64 nodes x 128 features into LDS (transposed).
        // stride-66 write bank = (j + q/2)%32 -> <=2 lanes/bank (free).
        for (int i = tid; i < 64 * HH; i += 256) {
            const int q = i >> 7, j = i & 127, n = n0 + q;
            float hv = x_seq[n * TT + t] * W_in[j] + m_seq[n * TT + t] * W_in[HH + j] + b_in[j];
            hv = hv > 0.f ? hv : 0.f;
            hb[j * 66 + q] = f2b(hv);
        }
        __syncthreads();
        // coalesced sigma-permuted stores: 8B chunks (2xu32 LDS reads)
        short* dst = hinT_all + (size_t)t * SLICE;
        for (int c = tid; c < 128 * 16; c += 256) {
            const int j = c >> 4, off = (c & 15) * 4;
            const int nb = n0 + off;
            const int tcol = (nb & ~31) | (((nb >> 2) & 3) << 3) | (((nb >> 4) & 1) << 2);
            const unsigned lo = *(const unsigned*)&hb[j * 66 + off];
            const unsigned hi = *(const unsigned*)&hb[j * 66 + off + 2];
            const u64 v = (u64)lo | ((u64)hi << 32);
            *(u64*)&dst[(size_t)j * NNP + tcol] = v;
        }
    }
}

// ===========================================================================
// Phase A: attention partials. 512 blocks x 256 thr (4 waves), 2 blocks/CU.
// XCD-local indexing: split = bid>>6, qg = bid&63 -> bid%8 = qg%8, so all 8
// split-producers of a qg share one XCD's L2 (OpartB/lpart stay local).
// KEY-SPLIT WAVES (R11): wave w = (qh = w&1, kh = w>>1) computes q rows
// [qg*64 + qh*32, +32) as 2 q-tiles, on key tiles kt with kt>>3 == kh.
// Per tile-phase: 2 active waves x 34 MFMAs = 68 (same density as before)
// with HALF the LDS frag reads (16 reads serve 34 MFMAs, not 17).
// Inactive waves stage + barrier.  Post-loop: key-halves merge in fp32 via
// LDS (obuf, stride 132 = bank-clean), l through a 64-float slot, then an
// all-thread coalesced bf16 convert + store.  Swapped QK^T -> in-register
// f2b softmax -> PV via sigma; l on the matrix pipe (ones column).
// ===========================================================================
__global__ __launch_bounds__(256, 2) void attn_kernel(
    const short* __restrict__ hp, const short* __restrict__ hinT,
    short* __restrict__ OpartB, float* __restrict__ lpart)
{
    __shared__ __align__(16) char pool[38144];
    short* KtS = (short*)pool;                  // [2][32*136]  17408 B
    short* VtS = (short*)(pool + 17408);        // [2][128*40]  20480 B
    float* obuf = (float*)pool;                 // [64][132] fp32, 33792 B (post-loop)
    float* lbuf = (float*)(pool + 33792);       // [64] fp32 (post-loop)

    const int tid  = threadIdx.x;
    const int wave = tid >> 6, lane = tid & 63;
    const int ln = lane & 15, g = lane >> 4;
    const int split = blockIdx.x >> 6, qg = blockIdx.x & 63;   // XCD = qg%8
    const int qh = wave & 1, kh = wave >> 1;
    const int q0 = qg * QB + qh * 32;
    const int kbase = split * KPB;

    // staging thread maps (256 threads, 16B/lane coalesced, 2 passes each)
    const int krow = tid >> 4, kcol = (tid & 15) * 8;   // rows 0..15 (+16)
    const int vrow = tid >> 2, vcol = (tid & 3) * 8;    // rows 0..63 (+64)

    // Q fragments (B-operand in swapped QK^T): 2 q-tiles, proven layout
    short8 qf[2][4];
    #pragma unroll
    for (int qt = 0; qt < 2; ++qt)
        #pragma unroll
        for (int kc = 0; kc < 4; ++kc)
            qf[qt][kc] = *(const short8*)&hp[(q0 + qt * 16 + ln) * HH + kc * 32 + g * 8];

    f32x4 oacc[2][8] = {};   // O[q = qt*16 + g*4 + r][d = dt*16 + ln]
    f32x4 lacc[2] = {};      // l (ones-column accumulator, matrix pipe)
    short8 vone;
    #pragma unroll
    for (int e = 0; e < 8; ++e) vone[e] = (short)0x3F80;   // bf16 1.0

    short8 ksA0, ksA1, vsA0, vsA1;
    auto load_tile = [&](int kt_) {
        const int kb = kbase + kt_ * KT;
        ksA0 = *(const short8*)&hp  [(kb + krow) * HH + kcol];
        ksA1 = *(const short8*)&hp  [(kb + krow + 16) * HH + kcol];
        vsA0 = *(const short8*)&hinT[(size_t)vrow * NNP + kb + vcol];
        vsA1 = *(const short8*)&hinT[(size_t)(vrow + 64) * NNP + kb + vcol];
    };
    auto store_tile = [&](int b) {
        *(short8*)&KtS[b * 4352 + krow * 136 + kcol]        = ksA0;
        *(short8*)&KtS[b * 4352 + (krow + 16) * 136 + kcol] = ksA1;
        *(short8*)&VtS[b * 5120 + vrow * 40 + vcol]         = vsA0;
        *(short8*)&VtS[b * 5120 + (vrow + 64) * 40 + vcol]  = vsA1;
    };

    load_tile(0);
    store_tile(0);

    for (int kt = 0; kt < NTILES; ++kt) {
        const int b = kt & 1;
        __syncthreads();   // buf b staged; prev iter's frag reads drained (WAR)

        const bool act = ((kt >> 3) == kh);
        short8 kf[2][4], vf[8];
        if (act) {
            #pragma unroll
            for (int kt2 = 0; kt2 < 2; ++kt2)
                #pragma unroll
                for (int kc = 0; kc < 4; ++kc)
                    kf[kt2][kc] = *(const short8*)&KtS[b * 4352 + (kt2 * 16 + ln) * 136 + kc * 32 + g * 8];
            #pragma unroll
            for (int dt = 0; dt < 8; ++dt)
                vf[dt] = *(const short8*)&VtS[b * 5120 + (dt * 16 + ln) * 40 + g * 8];
        }

        if (kt + 1 < NTILES) load_tile(kt + 1);   // global -> regs, overlaps compute

        short8 pa[2];
        if (act) {
            // swapped scores: st[kt2][qt][r] = S[key = kt2*16+g*4+r][q = qt*16+ln]
            f32x4 st[2][2] = {};
            __builtin_amdgcn_s_setprio(1);
            #pragma unroll
            for (int kt2 = 0; kt2 < 2; ++kt2)
                #pragma unroll
                for (int qt = 0; qt < 2; ++qt)
                    #pragma unroll
                    for (int kc = 0; kc < 4; ++kc)
                        st[kt2][qt] = MFMA(kf[kt2][kc], qf[qt][kc], st[kt2][qt]);
            __builtin_amdgcn_s_setprio(0);

            // fixed-shift softmax numerators -> bf16 A-fragments (proven order)
            #pragma unroll
            for (int qt = 0; qt < 2; ++qt) {
                short8 paq;
                #pragma unroll
                for (int e = 0; e < 8; ++e) {
                    const float s = (e < 4) ? st[0][qt][e] : st[1][qt][e - 4];
                    paq[e] = f2b(__expf(s * SCALE - CSHIFT));
                }
                pa[qt] = paq;
            }
        }

        if (kt + 1 < NTILES) store_tile(b ^ 1);

        if (act) {
            // PV (+ l via ones column): pa[qt] is the A-fragment in slot space
            __builtin_amdgcn_s_setprio(1);
            #pragma unroll
            for (int qt = 0; qt < 2; ++qt) {
                #pragma unroll
                for (int dt = 0; dt < 8; ++dt)
                    oacc[qt][dt] = MFMA(pa[qt], vf[dt], oacc[qt][dt]);
                lacc[qt] = MFMA(pa[qt], vone, lacc[qt]);
            }
            __builtin_amdgcn_s_setprio(0);
        }
    }

    __syncthreads();   // all waves' LDS frag reads done -> pool reusable as obuf

    // ---- cross-key-half merge in fp32 via LDS ----
    // row = qh*32 + qt*16 + g*4 + r; col = dt*16 + ln; stride 132 (bank-clean)
    if (kh == 0) {
        #pragma unroll
        for (int qt = 0; qt < 2; ++qt) {
            #pragma unroll
            for (int dt = 0; dt < 8; ++dt)
                #pragma unroll
                for (int r = 0; r < 4; ++r)
                    obuf[(qh * 32 + qt * 16 + g * 4 + r) * 132 + dt * 16 + ln] = oacc[qt][dt][r];
            if (ln == 0) {
                #pragma unroll
                for (int r = 0; r < 4; ++r)
                    lbuf[qh * 32 + qt * 16 + g * 4 + r] = lacc[qt][r];
            }
        }
    }
    __syncthreads();   // RAW: kh=0 partials visible to kh=1 waves
    if (kh == 1) {
        #pragma unroll
        for (int qt = 0; qt < 2; ++qt) {
            #pragma unroll
            for (int dt = 0; dt < 8; ++dt)
                #pragma unroll
                for (int r = 0; r < 4; ++r)
                    obuf[(qh * 32 + qt * 16 + g * 4 + r) * 132 + dt * 16 + ln] += oacc[qt][dt][r];
            if (ln == 0) {
                #pragma unroll
                for (int r = 0; r < 4; ++r) {
                    const int row = qh * 32 + qt * 16 + g * 4 + r;
                    lpart[split * NN + qg * QB + row] = lbuf[row] + lacc[qt][r];
                }
            }
        }
    }
    __syncthreads();   // RAW: merged O complete before convert/store

    // final: all threads convert merged fp32 -> bf16, coalesced 16B stores
    for (int c = tid; c < QB * 16; c += 256) {
        const int row = c >> 4, chunk = c & 15;
        const float* src = &obuf[row * 132 + chunk * 8];
        short8 rd;
        #pragma unroll
        for (int k = 0; k < 8; ++k) rd[k] = f2b(src[k]);
        *(short8*)&OpartB[((size_t)split * NN + qg * QB + row) * HH + chunk * 8] = rd;
    }
}

// ===========================================================================
// Phase B: merge 8 bf16 partials -> msg; h_new = relu(msg@Wg+b_gcn+h_in(t));
// pred -> out[:,t]; h_proj(t+1) -> hp.  (h_in precomputed in prep.)
// 256 blocks x 512 thr (8 waves, 2/SIMD — R6/R7-proven 8-wave GEMM content).
// XCD-local bijection: qg = (fb&7)+8*(fb>>5), sub = (fb>>3)&3 -> fb%8 = qg%8,
// so this block reads OpartB/lpart from its own XCD's L2.
// ===========================================================================
__global__ __launch_bounds__(512) void fuse_kernel(
    const short* __restrict__ OpartB, const float* __restrict__ lpart,
    short* __restrict__ hp,
    const short* __restrict__ WgT, const short* __restrict__ WpT,
    const float* __restrict__ b_gcn, const float* __restrict__ b_proj,
    const float* __restrict__ W_out, const float* __restrict__ b_out,
    const float* __restrict__ x_seq, const float* __restrict__ m_seq,
    const float* __restrict__ W_in,  const float* __restrict__ b_in,
    float* __restrict__ out, int t)
{
    __shared__ __align__(16) short msgb[16 * 136];
    __shared__ __align__(16) short hnb[16 * 136];
    __shared__ float larr[16];
    __shared__ float ppd[8 * 16];

    const int tid = threadIdx.x;
    const int wave = tid >> 6, lane = tid & 63;
    const int ln = lane & 15, g = lane >> 4;
    const int fb = blockIdx.x;
    const int qg64 = (fb & 7) + 8 * (fb >> 5);          // qg%8 = fb%8 (XCD-local)
    const int qb = qg64 * 64 + ((fb >> 3) & 3) * 16;    // bijective over 0..255

    if (tid < 16) {
        float l = 0.f;
        #pragma unroll
        for (int sp = 0; sp < SPLITS; ++sp) l += lpart[sp * NN + qb + tid];
        larr[tid] = 1.0f / l;
    }
    __syncthreads();

    // merge 8 bf16 partials -> msg (256 thr path, proven)
    if (tid < 256) {
        const int q = tid >> 4, c8 = (tid & 15) * 8;
        float s[8] = {0.f, 0.f, 0.f, 0.f, 0.f, 0.f, 0.f, 0.f};
        #pragma unroll
        for (int sp = 0; sp < SPLITS; ++sp) {
            const short8 v = *(const short8*)&OpartB[((size_t)sp * NN + qb + q) * HH + c8];
            #pragma unroll
            for (int k = 0; k < 8; ++k) s[k] += b2f(v[k]);
        }
        const float inv = larr[q];
        short* mp = &msgb[q * 136 + c8];
        #pragma unroll
        for (int k = 0; k < 8; ++k) mp[k] = f2b(s[k] * inv);
    }
    __syncthreads();

    // GEMM1 (8 waves, nt = wave): h_new = relu(msg@Wg + b_gcn + h_in(t))
    {
        short8 af[4];
        #pragma unroll
        for (int kc = 0; kc < 4; ++kc)
            af[kc] = *(const short8*)&msgb[ln * 136 + kc * 32 + g * 8];
        f32x4 c = {};
        #pragma unroll
        for (int kc = 0; kc < 4; ++kc)
            c = MFMA(af[kc], *(const short8*)&WgT[(wave * 16 + ln) * HH + kc * 32 + g * 8], c);
        const int j = wave * 16 + ln;
        const float bg = b_gcn[j], wo = W_out[j];
        const float wj0 = W_in[j], wj1 = W_in[HH + j], bj = b_in[j];
        float pr[4];
        #pragma unroll
        for (int r = 0; r < 4; ++r) {
            const int q = g * 4 + r;
            float hv = x_seq[(qb + q) * TT + t] * wj0 + m_seq[(qb + q) * TT + t] * wj1 + bj;
            hv = hv > 0.f ? hv : 0.f;
            float v = c[r] + bg + b2f(f2b(hv));
            v = v > 0.f ? v : 0.f;
            hnb[q * 136 + j] = f2b(v);
            pr[r] = v * wo;
        }
        #pragma unroll
        for (int r = 0; r < 4; ++r) {
            float p = pr[r];
            p += __shfl_xor(p, 1); p += __shfl_xor(p, 2);
            p += __shfl_xor(p, 4); p += __shfl_xor(p, 8);
            if (ln == 0) ppd[wave * 16 + g * 4 + r] = p;
        }
    }
    __syncthreads();   // hnb + ppd complete

    if (tid < 16) {
        float s = b_out[0];
        #pragma unroll
        for (int w = 0; w < 8; ++w) s += ppd[w * 16 + tid];
        out[(qb + tid) * TT + t] = s;
    }

    if (t < TT - 1) {
        // GEMM2 (8 waves, nt = wave): h_proj(t+1) = h_new @ W_proj + b_proj
        short8 hf[4];
        #pragma unroll
        for (int kc = 0; kc < 4; ++kc)
            hf[kc] = *(const short8*)&hnb[ln * 136 + kc * 32 + g * 8];
        f32x4 c = {};
        #pragma unroll
        for (int kc = 0; kc < 4; ++kc)
            c = MFMA(hf[kc], *(const short8*)&WpT[(wave * 16 + ln) * HH + kc * 32 + g * 8], c);
        const float bp = b_proj[wave * 16 + ln];
        #pragma unroll
        for (int r = 0; r < 4; ++r)
            hp[(qb + g * 4 + r) * HH + wave * 16 + ln] = f2b(c[r] + bp);
    }
}

// ===========================================================================
extern "C" void kernel_launch(void* const* d_in, const int* in_sizes, int n_in,
                              void* d_out, int out_size, void* d_ws, size_t ws_size,
                              hipStream_t stream) {
    const float* x_seq  = (const float*)d_in[0];
    const float* m_seq  = (const float*)d_in[1];
    const float* W_in   = (const float*)d_in[2];
    const float* b_in   = (const float*)d_in[3];
    const float* W_proj = (const float*)d_in[4];
    const float* b_proj = (const float*)d_in[5];
    const float* W_gcn  = (const float*)d_in[6];
    const float* b_gcn  = (const float*)d_in[7];
    const float* W_out  = (const float*)d_in[8];
    const float* b_out  = (const float*)d_in[9];
    float* out = (float*)d_out;

    // ws carve (~100 MB of the 256 MiB workspace):
    //   hp @0 | WgT/WpT/lpart @3MB | OpartB @4MB (8MB) | hinT_all @32MB (67MB)
    char* base = (char*)d_ws;
    const size_t MB = 1 << 20;
    short* hp       = (short*)(base + 0 * MB);
    short* WgT      = (short*)(base + 3 * MB);
    short* WpT      = (short*)(base + 3 * MB + 32768);
    float* lpart    = (float*)(base + 3 * MB + 65536);   // 8*4096*4 = 128 KB
    short* OpartB   = (short*)(base + 4 * MB);           // 8*4096*128*2 = 8 MB
    short* hinT_all = (short*)(base + 32 * MB);          // 64*128*4160*2 ≈ 67 MB

    prep_kernel<<<272 + 64 * 64, 256, 0, stream>>>(x_seq, m_seq, W_in, b_in,
                                                   W_proj, b_proj, W_gcn,
                                                   hp, hinT_all, WgT, WpT);

    for (int t = 0; t < TT; ++t) {
        const short* hinT_t = hinT_all + (size_t)t * SLICE;
        attn_kernel<<<(NN / QB) * SPLITS, 256, 0, stream>>>(hp, hinT_t, OpartB, lpart);
        fuse_kernel<<<NN / 16, 512, 0, stream>>>(OpartB, lpart, hp,
                                                 WgT, WpT, b_gcn, b_proj, W_out, b_out,
                                                 x_seq, m_seq, W_in, b_in, out, t);
    }
}

// Round 12
// 1544.998 us; speedup vs baseline: 1.1577x; 1.1577x over previous
//
#include <hip/hip_runtime.h>
#include <math.h>

#define NN 4096
#define TT 64
#define HH 128
#define NNP 4160            // hinT row stride (shorts): 8320B kills 8KB L2 set-aliasing
#define SLICE (128 * NNP)   // shorts per hinT time-slice
#define SPLITS 8
#define KPB (NN / SPLITS)   // 512 keys per phase-A block
#define KT 64
#define NTILES (KPB / KT)   // 8
#define QB 64               // q rows per attn block (4 waves x 16)
#define SCALE 0.08838834764831845f   // 1/sqrt(128)
#define CSHIFT 16.0f

typedef __attribute__((ext_vector_type(8))) short short8;
typedef __attribute__((ext_vector_type(4))) float f32x4;
typedef unsigned long long u64;
#define MFMA(a, b, c)   __builtin_amdgcn_mfma_f32_16x16x32_bf16((a), (b), (c), 0, 0, 0)

// ---- bf16 helpers (RNE) ----
__device__ __forceinline__ short f2b(float f) {
    union { float f; unsigned u; } v; v.f = f;
    unsigned r = v.u + 0x7fffu + ((v.u >> 16) & 1u);
    return (short)(r >> 16);
}
__device__ __forceinline__ float b2f(short s) {
    union { unsigned u; float f; } v; v.u = ((unsigned)(unsigned short)s) << 16;
    return v.f;
}
// Wave-local LDS fence: completes ds ops + blocks compiler reordering of
// cross-lane LDS accesses without a block barrier.
__device__ __forceinline__ void lds_fence() {
    __asm__ __volatile__("s_waitcnt lgkmcnt(0)" ::: "memory");
}

// ===========================================================================
// hinT column permutation sigma (within each 32-column group):
//   column c holds node  sigma(c) = (c&4) ? 16 + 4*(c>>3) + (c&3)
//                                         :      4*(c>>3) + (c&3)
// Writers place node kk at column inv_sigma(kk) = ((kk>>2)&3)*8 +
// ((kk>>4)&1)*4 + (kk&3)  (maps aligned-4 node chunks -> aligned-4 columns).
// After swapped QK^T (st = MFMA(K,Q) -> D[key][q]), lane (ln,g) holds the 8
// P-values of its query for keys {4g..4g+3, 16+4g..16+4g+3} — exactly a
// 16x16x32 PV A-fragment under sigma on the key axis (dot-product axis:
// permuting BOTH operands is free).  R3-proven end to end.  l accumulates on
// the matrix pipe via a B=ones MFMA (R5-R8 proven).  cvt_pk inline asm
// BANNED (NaN R1/2/4).  Coop grid.sync BANNED (R6: L2 invalidation).
// R11 lesson: key-split waves REGRESSED (+11%) — MFMA issue is per-SIMD, so
// concentrating MFMAs on 2 of 4 waves doubles serial depth while 2 SIMDs
// idle.  Keep all 4 waves MFMA-active every phase.  R12: KT=64 halves the
// barrier count (17 -> 9) at identical per-wave work distribution.
// ===========================================================================

// ===========================================================================
// prep: once per launch. bf16 weight transposes; hp = b_proj (h0=0);
// hinT_all (64 slices, padded stride NNP, sigma-permuted columns) for ALL t.
// grid: 256 (hp) + 16 (weights) + 4096 (64 t x 64 n-groups, LDS-transposed).
// ===========================================================================
__global__ __launch_bounds__(256) void prep_kernel(
    const float* __restrict__ x_seq, const float* __restrict__ m_seq,
    const float* __restrict__ W_in,  const float* __restrict__ b_in,
    const float* __restrict__ W_proj,const float* __restrict__ b_proj,
    const float* __restrict__ W_gcn,
    short* __restrict__ hp, short* __restrict__ hinT_all,
    short* __restrict__ WgT, short* __restrict__ WpT)
{
    __shared__ __align__(16) short hb[128 * 66];   // [j][q], stride 66: bank-safe
    const int b = blockIdx.x, tid = threadIdx.x;
    if (b < 256) {
        const int n0 = b * 16;
        for (int i = tid; i < 16 * HH; i += 256) {
            const int q = i >> 7, j = i & 127, n = n0 + q;
            hp[n * HH + j] = f2b(b_proj[j]);
        }
    } else if (b < 272) {
        const int wb = b - 256;
        #pragma unroll
        for (int k = 0; k < 4; ++k) {
            const int idx = wb * 1024 + k * 256 + tid;   // = n*128 + kk
            const int n = idx >> 7, kk = idx & 127;
            WgT[idx] = f2b(W_gcn[kk * HH + n]);
            WpT[idx] = f2b(W_proj[kk * HH + n]);
        }
    } else {
        const int u = b - 272;
        const int t = u >> 6, n0 = (u & 63) * 64;
        // compute h_in for 64 nodes x 128 features into LDS (transposed).
        // stride-66 write bank = (j + q/2)%32 -> <=2 lanes/bank (free).
        for (int i = tid; i < 64 * HH; i += 256) {
            const int q = i >> 7, j = i & 127, n = n0 + q;
            float hv = x_seq[n * TT + t] * W_in[j] + m_seq[n * TT + t] * W_in[HH + j] + b_in[j];
            hv = hv > 0.f ? hv : 0.f;
            hb[j * 66 + q] = f2b(hv);
        }
        __syncthreads();
        // coalesced sigma-permuted stores: 8B chunks (2xu32 LDS reads)
        short* dst = hinT_all + (size_t)t * SLICE;
        for (int c = tid; c < 128 * 16; c += 256) {
            const int j = c >> 4, off = (c & 15) * 4;
            const int nb = n0 + off;
            const int tcol = (nb & ~31) | (((nb >> 2) & 3) << 3) | (((nb >> 4) & 1) << 2);
            const unsigned lo = *(const unsigned*)&hb[j * 66 + off];
            const unsigned hi = *(const unsigned*)&hb[j * 66 + off + 2];
            const u64 v = (u64)lo | ((u64)hi << 32);
            *(u64*)&dst[(size_t)j * NNP + tcol] = v;
        }
    }
}

// ===========================================================================
// Phase A: attention partials. 512 blocks x 256 thr (4 waves), 2 blocks/CU
// (LDS 70KB/block).  XCD-local indexing: split = bid>>6, qg = bid&63 ->
// bid%8 = qg%8, so all 8 split-producers of a qg share one XCD's L2.
// Each wave owns 16 q rows; ALL 4 waves MFMA-active every phase (R11 lesson).
// KT=64: block stages 64-key K + 128x64 V tiles double-buffered, ONE barrier
// per phase -> 9 barriers total (vs 17 at KT=32).  Per phase each wave does
// 4 key-16-tiles: QK (16 MFMA) -> f2b softmax -> 2 pa pairs -> PV (16 MFMA
// + 2 l-MFMA).  Same arithmetic order as R10 -> bit-identical output.
// ===========================================================================
__global__ __launch_bounds__(256, 2) void attn_kernel(
    const short* __restrict__ hp, const short* __restrict__ hinT,
    short* __restrict__ OpartB, float* __restrict__ lpart)
{
    __shared__ __align__(16) char pool[71680];
    short* KtS = (short*)pool;                  // [2][64*136]  34816 B
    short* VtS = (short*)(pool + 34816);        // [2][128*72]  36864 B

    const int tid  = threadIdx.x;
    const int wave = tid >> 6, lane = tid & 63;
    const int ln = lane & 15, g = lane >> 4;
    const int split = blockIdx.x >> 6, qg = blockIdx.x & 63;   // XCD = qg%8
    const int q0 = qg * QB + wave * 16;
    const int kbase = split * KPB;

    // staging thread maps (256 threads, 16B/lane coalesced, 4 passes each)
    const int krow = tid >> 4, kcol = (tid & 15) * 8;   // rows +16k, 128 shorts
    const int vrow = tid >> 3, vcol = (tid & 7) * 8;    // rows +32k, 64 shorts

    // Q fragment (B-operand in swapped QK^T): 1 q-tile, proven layout
    short8 qf[4];
    #pragma unroll
    for (int kc = 0; kc < 4; ++kc)
        qf[kc] = *(const short8*)&hp[(q0 + ln) * HH + kc * 32 + g * 8];

    f32x4 oacc[8] = {};   // O[q = g*4 + r][d = dt*16 + ln]
    f32x4 lacc = {};      // l (ones-column accumulator, matrix pipe)
    short8 vone;
    #pragma unroll
    for (int e = 0; e < 8; ++e) vone[e] = (short)0x3F80;   // bf16 1.0

    short8 ksA[4], vsA[4];
    auto load_tile = [&](int kt_) {
        const int kb = kbase + kt_ * KT;
        #pragma unroll
        for (int k = 0; k < 4; ++k)
            ksA[k] = *(const short8*)&hp[(kb + krow + 16 * k) * HH + kcol];
        #pragma unroll
        for (int k = 0; k < 4; ++k)
            vsA[k] = *(const short8*)&hinT[(size_t)(vrow + 32 * k) * NNP + kb + vcol];
    };
    auto store_tile = [&](int b) {
        #pragma unroll
        for (int k = 0; k < 4; ++k)
            *(short8*)&KtS[b * 8704 + (krow + 16 * k) * 136 + kcol] = ksA[k];
        #pragma unroll
        for (int k = 0; k < 4; ++k)
            *(short8*)&VtS[b * 9216 + (vrow + 32 * k) * 72 + vcol] = vsA[k];
    };

    load_tile(0);
    store_tile(0);

    for (int kt = 0; kt < NTILES; ++kt) {
        const int b = kt & 1;
        __syncthreads();   // buf b staged; prev iter's frag reads drained (WAR)

        // K fragments: 4 key-16-tiles (A-operand, proven read pattern)
        short8 kf[4][4];
        #pragma unroll
        for (int kt2 = 0; kt2 < 4; ++kt2)
            #pragma unroll
            for (int kc = 0; kc < 4; ++kc)
                kf[kt2][kc] = *(const short8*)&KtS[b * 8704 + (kt2 * 16 + ln) * 136 + kc * 32 + g * 8];

        if (kt + 1 < NTILES) load_tile(kt + 1);   // global -> regs, overlaps compute

        // swapped scores: st[kt2][r] = S[key = kt2*16+g*4+r][q = q0+ln]
        f32x4 st[4] = {};
        __builtin_amdgcn_s_setprio(1);
        #pragma unroll
        for (int kt2 = 0; kt2 < 4; ++kt2)
            #pragma unroll
            for (int kc = 0; kc < 4; ++kc)
                st[kt2] = MFMA(kf[kt2][kc], qf[kc], st[kt2]);
        __builtin_amdgcn_s_setprio(0);

        // fixed-shift softmax numerators -> bf16 A-fragments, one per 32-key
        // pair p (keys [kb+p*32, +32), 32-aligned -> sigma grouping intact)
        short8 pa[2];
        #pragma unroll
        for (int p = 0; p < 2; ++p) {
            short8 paq;
            #pragma unroll
            for (int e = 0; e < 8; ++e) {
                const float s = (e < 4) ? st[2 * p][e] : st[2 * p + 1][e - 4];
                paq[e] = f2b(__expf(s * SCALE - CSHIFT));
            }
            pa[p] = paq;
        }

        if (kt + 1 < NTILES) store_tile(b ^ 1);

        // V^T fragments (slot space) + PV (+ l via ones column)
        #pragma unroll
        for (int p = 0; p < 2; ++p) {
            short8 vf[8];
            #pragma unroll
            for (int dt = 0; dt < 8; ++dt)
                vf[dt] = *(const short8*)&VtS[b * 9216 + (dt * 16 + ln) * 72 + p * 32 + g * 8];
            __builtin_amdgcn_s_setprio(1);
            #pragma unroll
            for (int dt = 0; dt < 8; ++dt)
                oacc[dt] = MFMA(pa[p], vf[dt], oacc[dt]);
            lacc = MFMA(pa[p], vone, lacc);
            __builtin_amdgcn_s_setprio(0);
        }
    }

    __syncthreads();   // all waves' LDS frag reads done -> pool reusable as bounce

    // l: ones-column output is col-replicated; row q = g*4 + r (proven D map)
    if (ln == 0) {
        #pragma unroll
        for (int r = 0; r < 4; ++r)
            lpart[split * NN + q0 + g * 4 + r] = lacc[r];
    }

    // O partials -> bf16 via per-wave LDS bounce (coalesced 16B/lane stores)
    short* bounce = (short*)pool + wave * 2048;   // 4KB/wave in dead Kt/Vt
    #pragma unroll
    for (int dt = 0; dt < 8; ++dt)
        #pragma unroll
        for (int r = 0; r < 4; ++r)
            bounce[(g * 4 + r) * 128 + dt * 16 + ln] = f2b(oacc[dt][r]);
    lds_fence();   // RAW: cross-lane bounce writes before row reads
    #pragma unroll
    for (int sub = 0; sub < 4; ++sub) {
        const int qrow = sub * 4 + (lane >> 4), chunk = lane & 15;
        const short8 rd = *(const short8*)&bounce[qrow * 128 + chunk * 8];
        *(short8*)&OpartB[((size_t)split * NN + q0 + qrow) * HH + chunk * 8] = rd;
    }
}

// ===========================================================================
// Phase B: merge 8 bf16 partials -> msg; h_new = relu(msg@Wg+b_gcn+h_in(t));
// pred -> out[:,t]; h_proj(t+1) -> hp.  (h_in precomputed in prep.)
// 256 blocks x 512 thr (8 waves, 2/SIMD — R6/R7-proven 8-wave GEMM content).
// XCD-local bijection: qg = (fb&7)+8*(fb>>5), sub = (fb>>3)&3 -> fb%8 = qg%8,
// so this block reads OpartB/lpart from its own XCD's L2.
// ===========================================================================
__global__ __launch_bounds__(512) void fuse_kernel(
    const short* __restrict__ OpartB, const float* __restrict__ lpart,
    short* __restrict__ hp,
    const short* __restrict__ WgT, const short* __restrict__ WpT,
    const float* __restrict__ b_gcn, const float* __restrict__ b_proj,
    const float* __restrict__ W_out, const float* __restrict__ b_out,
    const float* __restrict__ x_seq, const float* __restrict__ m_seq,
    const float* __restrict__ W_in,  const float* __restrict__ b_in,
    float* __restrict__ out, int t)
{
    __shared__ __align__(16) short msgb[16 * 136];
    __shared__ __align__(16) short hnb[16 * 136];
    __shared__ float larr[16];
    __shared__ float ppd[8 * 16];

    const int tid = threadIdx.x;
    const int wave = tid >> 6, lane = tid & 63;
    const int ln = lane & 15, g = lane >> 4;
    const int fb = blockIdx.x;
    const int qg64 = (fb & 7) + 8 * (fb >> 5);          // qg%8 = fb%8 (XCD-local)
    const int qb = qg64 * 64 + ((fb >> 3) & 3) * 16;    // bijective over 0..255

    if (tid < 16) {
        float l = 0.f;
        #pragma unroll
        for (int sp = 0; sp < SPLITS; ++sp) l += lpart[sp * NN + qb + tid];
        larr[tid] = 1.0f / l;
    }
    __syncthreads();

    // merge 8 bf16 partials -> msg (256 thr path, proven)
    if (tid < 256) {
        const int q = tid >> 4, c8 = (tid & 15) * 8;
        float s[8] = {0.f, 0.f, 0.f, 0.f, 0.f, 0.f, 0.f, 0.f};
        #pragma unroll
        for (int sp = 0; sp < SPLITS; ++sp) {
            const short8 v = *(const short8*)&OpartB[((size_t)sp * NN + qb + q) * HH + c8];
            #pragma unroll
            for (int k = 0; k < 8; ++k) s[k] += b2f(v[k]);
        }
        const float inv = larr[q];
        short* mp = &msgb[q * 136 + c8];
        #pragma unroll
        for (int k = 0; k < 8; ++k) mp[k] = f2b(s[k] * inv);
    }
    __syncthreads();

    // GEMM1 (8 waves, nt = wave): h_new = relu(msg@Wg + b_gcn + h_in(t))
    {
        short8 af[4];
        #pragma unroll
        for (int kc = 0; kc < 4; ++kc)
            af[kc] = *(const short8*)&msgb[ln * 136 + kc * 32 + g * 8];
        f32x4 c = {};
        #pragma unroll
        for (int kc = 0; kc < 4; ++kc)
            c = MFMA(af[kc], *(const short8*)&WgT[(wave * 16 + ln) * HH + kc * 32 + g * 8], c);
        const int j = wave * 16 + ln;
        const float bg = b_gcn[j], wo = W_out[j];
        const float wj0 = W_in[j], wj1 = W_in[HH + j], bj = b_in[j];
        float pr[4];
        #pragma unroll
        for (int r = 0; r < 4; ++r) {
            const int q = g * 4 + r;
            float hv = x_seq[(qb + q) * TT + t] * wj0 + m_seq[(qb + q) * TT + t] * wj1 + bj;
            hv = hv > 0.f ? hv : 0.f;
            float v = c[r] + bg + b2f(f2b(hv));
            v = v > 0.f ? v : 0.f;
            hnb[q * 136 + j] = f2b(v);
            pr[r] = v * wo;
        }
        #pragma unroll
        for (int r = 0; r < 4; ++r) {
            float p = pr[r];
            p += __shfl_xor(p, 1); p += __shfl_xor(p, 2);
            p += __shfl_xor(p, 4); p += __shfl_xor(p, 8);
            if (ln == 0) ppd[wave * 16 + g * 4 + r] = p;
        }
    }
    __syncthreads();   // hnb + ppd complete

    if (tid < 16) {
        float s = b_out[0];
        #pragma unroll
        for (int w = 0; w < 8; ++w) s += ppd[w * 16 + tid];
        out[(qb + tid) * TT + t] = s;
    }

    if (t < TT - 1) {
        // GEMM2 (8 waves, nt = wave): h_proj(t+1) = h_new @ W_proj + b_proj
        short8 hf[4];
        #pragma unroll
        for (int kc = 0; kc < 4; ++kc)
            hf[kc] = *(const short8*)&hnb[ln * 136 + kc * 32 + g * 8];
        f32x4 c = {};
        #pragma unroll
        for (int kc = 0; kc < 4; ++kc)
            c = MFMA(hf[kc], *(const short8*)&WpT[(wave * 16 + ln) * HH + kc * 32 + g * 8], c);
        const float bp = b_proj[wave * 16 + ln];
        #pragma unroll
        for (int r = 0; r < 4; ++r)
            hp[(qb + g * 4 + r) * HH + wave * 16 + ln] = f2b(c[r] + bp);
    }
}

// ===========================================================================
extern "C" void kernel_launch(void* const* d_in, const int* in_sizes, int n_in,
                              void* d_out, int out_size, void* d_ws, size_t ws_size,
                              hipStream_t stream) {
    const float* x_seq  = (const float*)d_in[0];
    const float* m_seq  = (const float*)d_in[1];
    const float* W_in   = (const float*)d_in[2];
    const float* b_in   = (const float*)d_in[3];
    const float* W_proj = (const float*)d_in[4];
    const float* b_proj = (const float*)d_in[5];
    const float* W_gcn  = (const float*)d_in[6];
    const float* b_gcn  = (const float*)d_in[7];
    const float* W_out  = (const float*)d_in[8];
    const float* b_out  = (const float*)d_in[9];
    float* out = (float*)d_out;

    // ws carve (~100 MB of the 256 MiB workspace):
    //   hp @0 | WgT/WpT/lpart @3MB | OpartB @4MB (8MB) | hinT_all @32MB (67MB)
    char* base = (char*)d_ws;
    const size_t MB = 1 << 20;
    short* hp       = (short*)(base + 0 * MB);
    short* WgT      = (short*)(base + 3 * MB);
    short* WpT      = (short*)(base + 3 * MB + 32768);
    float* lpart    = (float*)(base + 3 * MB + 65536);   // 8*4096*4 = 128 KB
    short* OpartB   = (short*)(base + 4 * MB);           // 8*4096*128*2 = 8 MB
    short* hinT_all = (short*)(base + 32 * MB);          // 64*128*4160*2 ≈ 67 MB

    prep_kernel<<<272 + 64 * 64, 256, 0, stream>>>(x_seq, m_seq, W_in, b_in,
                                                   W_proj, b_proj, W_gcn,
                                                   hp, hinT_all, WgT, WpT);

    for (int t = 0; t < TT; ++t) {
        const short* hinT_t = hinT_all + (size_t)t * SLICE;
        attn_kernel<<<(NN / QB) * SPLITS, 256, 0, stream>>>(hp, hinT_t, OpartB, lpart);
        fuse_kernel<<<NN / 16, 512, 0, stream>>>(OpartB, lpart, hp,
                                                 WgT, WpT, b_gcn, b_proj, W_out, b_out,
                                                 x_seq, m_seq, W_in, b_in, out, t);
    }
}